// Round 14
// baseline (73.575 us; speedup 1.0000x reference)
//
#include <hip/hip_runtime.h>

#define F 128
#define NO 256            // NUM_IRREPS = 2*F
#define CHUNK 32
#define THREADS 512
#define NBLK_HIST 64

typedef short bf16x8 __attribute__((ext_vector_type(8)));
typedef float f32x4 __attribute__((ext_vector_type(4)));
typedef unsigned short u16x8 __attribute__((ext_vector_type(8)));

// ws int layout
#define WS_COUNTS   0      // 64 ints
#define WS_OFFSETS  64
#define WS_NCHUNKS  192
#define WS_DESC     256    // 3 ints per chunk
#define WS_BC       8192   // [64 hist-blocks][64 species]
#define WS_ORDER    16384  // N ints
// ws byte offsets (weight panels)
#define WS_GKFRAG  (1u<<20)             // [S*16 ot][4 kk][64 lane][8] bf16 = 4MB
#define WS_LW0FRAG (5u<<20)             // [8 gt][4 kk][64][8] bf16 = 32KB
#define WS_LW1FRAG ((5u<<20) + 32768)

__device__ __forceinline__ unsigned short f2bf(float x) {
    union { float f; unsigned u; } v; v.f = x;
    unsigned r = (v.u + 0x7FFFu + ((v.u >> 16) & 1u)) >> 16;
    return (unsigned short)r;
}
__device__ __forceinline__ unsigned pack2(float a, float b) {
    return (unsigned)f2bf(a) | ((unsigned)f2bf(b) << 16);
}
__device__ __forceinline__ float bf2f(unsigned short h) {
    union { unsigned u; float f; } v; v.u = ((unsigned)h) << 16; return v.f;
}

// ---- prep: weight fragments (and zero counts) ----
__global__ __launch_bounds__(256) void k_prep(const float* __restrict__ gk,
                                              const float* __restrict__ lw0,
                                              const float* __restrict__ lw1,
                                              int* __restrict__ wsI,
                                              unsigned* __restrict__ gkfrag,
                                              unsigned* __restrict__ lw0f,
                                              unsigned* __restrict__ lw1f,
                                              int S) {
    int t = threadIdx.x, lane = t & 63, grp = t >> 6;
    int lr = lane & 15, lg = lane >> 4;
    int b = blockIdx.x;
    if (b < S) {
        const float* src = gk + (size_t)b * F * NO;
        #pragma unroll
        for (int it = 0; it < 4; ++it) {
            int ot = grp * 4 + it;
            #pragma unroll
            for (int kk = 0; kk < 4; ++kk) {
                float v[8];
                #pragma unroll
                for (int e = 0; e < 8; ++e)
                    v[e] = src[(kk * 32 + lg * 8 + e) * NO + ot * 16 + lr];
                uint4 pk;
                pk.x = pack2(v[0], v[1]); pk.y = pack2(v[2], v[3]);
                pk.z = pack2(v[4], v[5]); pk.w = pack2(v[6], v[7]);
                *(uint4*)((char*)gkfrag + ((size_t)((b * 16 + ot) * 4 + kk) * 1024) + lane * 16) = pk;
            }
        }
    } else if (b == S || b == S + 1) {
        const float* src = (b == S) ? lw0 : lw1;
        unsigned* dst = (b == S) ? lw0f : lw1f;
        const float inv = 0.08838834764831845f; // 1/sqrt(128)
        #pragma unroll
        for (int it = 0; it < 2; ++it) {
            int gt = grp * 2 + it;
            #pragma unroll
            for (int kk = 0; kk < 4; ++kk) {
                float v[8];
                #pragma unroll
                for (int e = 0; e < 8; ++e)
                    v[e] = src[(kk * 32 + lg * 8 + e) * F + gt * 16 + lr] * inv;
                uint4 pk;
                pk.x = pack2(v[0], v[1]); pk.y = pack2(v[2], v[3]);
                pk.z = pack2(v[4], v[5]); pk.w = pack2(v[6], v[7]);
                *(uint4*)((char*)dst + ((gt * 4 + kk) * 1024) + lane * 16) = pk;
            }
        }
        if (b == S && t < 64) wsI[WS_COUNTS + t] = 0;
    }
}

// ---- hist: per-block counts + global counts ----
__global__ void k_hist(const int* __restrict__ spec, int N, int* __restrict__ wsI) {
    __shared__ int h[64];
    int t = threadIdx.x, b = blockIdx.x;
    if (t < 64) h[t] = 0;
    __syncthreads();
    int per = (N + NBLK_HIST - 1) / NBLK_HIST;
    int lo = b * per, hi = min(N, lo + per);
    for (int i = lo + t; i < hi; i += 256) atomicAdd(&h[spec[i]], 1);
    __syncthreads();
    if (t < 64) {
        wsI[WS_BC + b * 64 + t] = h[t];
        if (h[t]) atomicAdd(&wsI[WS_COUNTS + t], h[t]);
    }
}

// ---- plan: prefix sums, per-block bases, chunk descriptors ----
__global__ void k_plan(int* __restrict__ wsI, int S) {
    int t = threadIdx.x;
    int cnt = (t < S) ? wsI[WS_COUNTS + t] : 0;
    int nch = (cnt + CHUNK - 1) / CHUNK;
    int x = cnt, y = nch;
    #pragma unroll
    for (int d = 1; d < 64; d <<= 1) {
        int vx = __shfl_up(x, d);
        int vy = __shfl_up(y, d);
        if (t >= d) { x += vx; y += vy; }
    }
    int off = x - cnt, cbase = y - nch;
    if (t < S) {
        wsI[WS_OFFSETS + t] = off;
        int run = off;
        for (int b2 = 0; b2 < NBLK_HIST; ++b2) {
            int tmp = wsI[WS_BC + b2 * 64 + t];
            wsI[WS_BC + b2 * 64 + t] = run;
            run += tmp;
        }
        for (int c = 0; c < nch; ++c) {
            int* dsc = &wsI[WS_DESC + 3 * (cbase + c)];
            dsc[0] = t;
            dsc[1] = off + c * CHUNK;
            dsc[2] = min(CHUNK, cnt - c * CHUNK);
        }
    }
    if (t == 63) wsI[WS_NCHUNKS] = y;
}

// ---- scatter: blockwise deterministic-range scatter ----
__global__ void k_scatter(const int* __restrict__ spec, int N, int* __restrict__ wsI) {
    __shared__ int cur[64];
    int t = threadIdx.x, b = blockIdx.x;
    if (t < 64) cur[t] = wsI[WS_BC + b * 64 + t];
    __syncthreads();
    int per = (N + NBLK_HIST - 1) / NBLK_HIST;
    int lo = b * per, hi = min(N, lo + per);
    for (int i = lo + t; i < hi; i += 256) {
        int pos = atomicAdd(&cur[spec[i]], 1);
        wsI[WS_ORDER + pos] = i;
    }
}

// ---- main: one 32-node chunk per block, 512 THREADS (8 waves).
// Same LDS/traffic/barriers as R11/R13 but each thread does half the work:
// thread = one (node, 8-feature group) in phases 1/3; each wave owns 2 gate
// panels (phase 2) and 1 output column-tile (phase 4). Waves/CU: 12 -> 24.
__global__ __launch_bounds__(THREADS, 6) void k_main(
    const float* __restrict__ nf,
    const float* __restrict__ w0,
    const float* __restrict__ w1,
    const unsigned short* __restrict__ gkfrag,
    const float* __restrict__ gb,
    const unsigned short* __restrict__ lw0f,
    const unsigned short* __restrict__ lw1f,
    const int* __restrict__ wsI,
    float* __restrict__ out)
{
    int b = blockIdx.x;
    if (b >= wsI[WS_NCHUNKS]) return;
    int s     = wsI[WS_DESC + 3 * b];
    int start = wsI[WS_DESC + 3 * b + 1];
    int cnt   = wsI[WS_DESC + 3 * b + 2];

    __shared__ __align__(16) unsigned short s_ab[32 * 136];      // out0 -> out0g bf16, 32 nodes
    __shared__ __align__(16) unsigned short s_o1[3 * 32 * 136];  // c1*x1 -> out1g bf16, 32 nodes
    __shared__ __align__(16) unsigned short s_gate[32 * 280];    // gate bf16, 32 nodes
    __shared__ int s_nid[CHUNK];

    int t = threadIdx.x;
    int lane = t & 63, w = t >> 6, lr = lane & 15, lg = lane >> 4;
    int n = t >> 4, j = t & 15, f0 = 8 * j;   // thread -> (node, feature-group)

    if (t < CHUNK) s_nid[t] = (t < cnt) ? wsI[WS_ORDER + start + t] : -1;

    int nid = (n < cnt) ? wsI[WS_ORDER + start + n] : -1;
    const float* p = nf + (size_t)(nid >= 0 ? nid : 0) * 512;

    // ---- phase 1: polynomial paths, one node per thread ----
    float x0[8], q[24], dot[8], o0[8], c1[8];
    *(float4*)&x0[0] = *(const float4*)&p[f0];
    *(float4*)&x0[4] = *(const float4*)&p[f0 + 4];
    #pragma unroll
    for (int v = 0; v < 6; ++v)
        *(float4*)&q[4 * v] = *(const float4*)&p[128 + 3 * f0 + 4 * v];
    if (nid < 0) {
        #pragma unroll
        for (int i = 0; i < 8; ++i) x0[i] = 0.f;
        #pragma unroll
        for (int i = 0; i < 24; ++i) q[i] = 0.f;
    }
    #pragma unroll
    for (int i = 0; i < 8; ++i)
        dot[i] = q[3 * i] * q[3 * i] + q[3 * i + 1] * q[3 * i + 1] + q[3 * i + 2] * q[3 * i + 2];

    {
        const float* W0 = w0 + s * 5 * F + f0;
        const float* W1 = w1 + s * 4 * F + f0;
        float wr[8];
        #define LOADW(base) { \
            *(float4*)&wr[0] = *(const float4*)&(base)[0]; \
            *(float4*)&wr[4] = *(const float4*)&(base)[4]; }
        LOADW(W0);
        #pragma unroll
        for (int i = 0; i < 8; ++i) o0[i] = x0[i] * wr[i];
        LOADW((W0 + F));
        #pragma unroll
        for (int i = 0; i < 8; ++i) o0[i] += x0[i] * x0[i] * wr[i];
        LOADW((W0 + 2 * F));
        #pragma unroll
        for (int i = 0; i < 8; ++i) o0[i] += dot[i] * wr[i];
        LOADW((W0 + 3 * F));
        #pragma unroll
        for (int i = 0; i < 8; ++i) o0[i] += x0[i] * x0[i] * x0[i] * wr[i];
        LOADW((W0 + 4 * F));
        #pragma unroll
        for (int i = 0; i < 8; ++i) o0[i] += x0[i] * dot[i] * wr[i];
        LOADW(W1);
        #pragma unroll
        for (int i = 0; i < 8; ++i) c1[i] = wr[i];
        LOADW((W1 + F));
        #pragma unroll
        for (int i = 0; i < 8; ++i) c1[i] += x0[i] * wr[i];
        LOADW((W1 + 2 * F));
        #pragma unroll
        for (int i = 0; i < 8; ++i) c1[i] += x0[i] * x0[i] * wr[i];
        LOADW((W1 + 3 * F));
        #pragma unroll
        for (int i = 0; i < 8; ++i) c1[i] += dot[i] * wr[i];
        #undef LOADW
    }
    {
        uint4 pk;
        pk.x = pack2(o0[0], o0[1]); pk.y = pack2(o0[2], o0[3]);
        pk.z = pack2(o0[4], o0[5]); pk.w = pack2(o0[6], o0[7]);
        *(uint4*)&s_ab[n * 136 + f0] = pk;
    }
    // ungated products c1*x1[d] -> s_o1 (gated in phase 3)
    #pragma unroll
    for (int d = 0; d < 3; ++d) {
        uint4 p1;
        p1.x = pack2(c1[0] * q[0 + d],  c1[1] * q[3 + d]);
        p1.y = pack2(c1[2] * q[6 + d],  c1[3] * q[9 + d]);
        p1.z = pack2(c1[4] * q[12 + d], c1[5] * q[15 + d]);
        p1.w = pack2(c1[6] * q[18 + d], c1[7] * q[21 + d]);
        *(uint4*)&s_o1[(d * 32 + n) * 136 + f0] = p1;
    }
    __syncthreads();   // B1: out0 + products ready (32 nodes)

    // ---- phase 2: gate; each wave owns 2 panels (ot = 2w, 2w+1) ----
    {
        #pragma unroll
        for (int oi = 0; oi < 2; ++oi) {
            int ot = 2 * w + oi;
            const unsigned short* gkb =
                gkfrag + ((size_t)((s * 16 + ot) * 4)) * 512 + lane * 8;
            bf16x8 Bf[4];
            #pragma unroll
            for (int kk = 0; kk < 4; ++kk)
                Bf[kk] = *(const bf16x8*)(gkb + kk * 512);
            float gbv = gb[s * NO + ot * 16 + lr];
            #pragma unroll
            for (int nt = 0; nt < 2; ++nt) {
                f32x4 acc; acc[0] = gbv; acc[1] = gbv; acc[2] = gbv; acc[3] = gbv;
                #pragma unroll
                for (int kk = 0; kk < 4; ++kk) {
                    bf16x8 A = *(const bf16x8*)&s_ab[(nt * 16 + lr) * 136 + kk * 32 + lg * 8];
                    acc = __builtin_amdgcn_mfma_f32_16x16x32_bf16(A, Bf[kk], acc, 0, 0, 0);
                }
                #pragma unroll
                for (int r = 0; r < 4; ++r)
                    s_gate[(nt * 16 + lg * 4 + r) * 280 + ot * 16 + lr] = f2bf(acc[r]);
            }
        }
    }
    __syncthreads();   // B2: gate ready (and all phase-2 LDS reads done)

    // ---- phase 3: apply gate in place, one node per thread ----
    {
        float g0[8], g1[8];
        u16x8 va = *(const u16x8*)&s_gate[n * 280 + f0];
        u16x8 vb = *(const u16x8*)&s_gate[n * 280 + 128 + f0];
        #pragma unroll
        for (int i = 0; i < 8; ++i) { g0[i] = bf2f(va[i]); g1[i] = bf2f(vb[i]); }
        {
            uint4 pk;
            pk.x = pack2(o0[0] * g0[0], o0[1] * g0[1]);
            pk.y = pack2(o0[2] * g0[2], o0[3] * g0[3]);
            pk.z = pack2(o0[4] * g0[4], o0[5] * g0[5]);
            pk.w = pack2(o0[6] * g0[6], o0[7] * g0[7]);
            *(uint4*)&s_ab[n * 136 + f0] = pk;
        }
        #pragma unroll
        for (int d = 0; d < 3; ++d) {
            unsigned short* pp = &s_o1[(d * 32 + n) * 136 + f0];
            u16x8 pr = *(const u16x8*)pp;
            uint4 pk;
            pk.x = pack2(bf2f(pr[0]) * g1[0], bf2f(pr[1]) * g1[1]);
            pk.y = pack2(bf2f(pr[2]) * g1[2], bf2f(pr[3]) * g1[3]);
            pk.z = pack2(bf2f(pr[4]) * g1[4], bf2f(pr[5]) * g1[5]);
            pk.w = pack2(bf2f(pr[6]) * g1[6], bf2f(pr[7]) * g1[7]);
            *(uint4*)pp = pk;
        }
    }
    __syncthreads();   // B3: out0g/out1g ready

    // ---- phase 4: each wave owns output column-tile gt = w ----
    {
        int gt = w;
        int nids[2][4];
        #pragma unroll
        for (int nt = 0; nt < 2; ++nt)
            #pragma unroll
            for (int r = 0; r < 4; ++r)
                nids[nt][r] = s_nid[nt * 16 + lg * 4 + r];

        {
            const unsigned short* l0b = lw0f + (size_t)(gt * 4) * 512 + lane * 8;
            bf16x8 Lf[4];
            #pragma unroll
            for (int kk = 0; kk < 4; ++kk)
                Lf[kk] = *(const bf16x8*)(l0b + kk * 512);
            #pragma unroll
            for (int nt = 0; nt < 2; ++nt) {
                f32x4 acc = {0.f, 0.f, 0.f, 0.f};
                #pragma unroll
                for (int kk = 0; kk < 4; ++kk) {
                    bf16x8 A2 = *(const bf16x8*)&s_ab[(nt * 16 + lr) * 136 + kk * 32 + lg * 8];
                    acc = __builtin_amdgcn_mfma_f32_16x16x32_bf16(A2, Lf[kk], acc, 0, 0, 0);
                }
                #pragma unroll
                for (int r = 0; r < 4; ++r)
                    if (nids[nt][r] >= 0)
                        out[(size_t)nids[nt][r] * 512 + gt * 16 + lr] = acc[r];
            }
        }
        {
            const unsigned short* l1b = lw1f + (size_t)(gt * 4) * 512 + lane * 8;
            bf16x8 Lf1[4];
            #pragma unroll
            for (int kk = 0; kk < 4; ++kk)
                Lf1[kk] = *(const bf16x8*)(l1b + kk * 512);
            #pragma unroll
            for (int d = 0; d < 3; ++d) {
                #pragma unroll
                for (int nt = 0; nt < 2; ++nt) {
                    f32x4 acc = {0.f, 0.f, 0.f, 0.f};
                    #pragma unroll
                    for (int kk = 0; kk < 4; ++kk) {
                        bf16x8 Ad = *(const bf16x8*)&s_o1[(d * 32 + nt * 16 + lr) * 136 + kk * 32 + lg * 8];
                        acc = __builtin_amdgcn_mfma_f32_16x16x32_bf16(Ad, Lf1[kk], acc, 0, 0, 0);
                    }
                    #pragma unroll
                    for (int r = 0; r < 4; ++r)
                        if (nids[nt][r] >= 0)
                            out[(size_t)nids[nt][r] * 512 + F + (gt * 16 + lr) * 3 + d] = acc[r];
                }
            }
        }
    }
}

extern "C" void kernel_launch(void* const* d_in, const int* in_sizes, int n_in,
                              void* d_out, int out_size, void* d_ws, size_t ws_size,
                              hipStream_t stream) {
    const float* nf  = (const float*)d_in[0];
    const int*  spec = (const int*)d_in[1];
    const float* w0  = (const float*)d_in[2];
    const float* w1  = (const float*)d_in[3];
    const float* gk  = (const float*)d_in[4];
    const float* gb  = (const float*)d_in[5];
    const float* lw0 = (const float*)d_in[6];
    const float* lw1 = (const float*)d_in[7];
    float* out = (float*)d_out;

    int N = in_sizes[0] / (4 * F);
    int S = in_sizes[5] / NO;
    int* wsI = (int*)d_ws;
    unsigned* gkfrag = (unsigned*)((char*)d_ws + WS_GKFRAG);
    unsigned* lw0f   = (unsigned*)((char*)d_ws + WS_LW0FRAG);
    unsigned* lw1f   = (unsigned*)((char*)d_ws + WS_LW1FRAG);

    k_prep<<<S + 2, 256, 0, stream>>>(gk, lw0, lw1, wsI, gkfrag, lw0f, lw1f, S);
    k_hist<<<NBLK_HIST, 256, 0, stream>>>(spec, N, wsI);
    k_plan<<<1, 64, 0, stream>>>(wsI, S);
    k_scatter<<<NBLK_HIST, 256, 0, stream>>>(spec, N, wsI);

    int maxc = (N + CHUNK - 1) / CHUNK + S;
    k_main<<<maxc, THREADS, 0, stream>>>(nf, w0, w1,
                                         (const unsigned short*)gkfrag, gb,
                                         (const unsigned short*)lw0f,
                                         (const unsigned short*)lw1f,
                                         wsI, out);
}

// Round 15
// 66.310 us; speedup vs baseline: 1.1096x; 1.1096x over previous
//
#include <hip/hip_runtime.h>

#define F 128
#define NO 256            // NUM_IRREPS = 2*F
#define CHUNK 32
#define THREADS 256
#define NBLK_HIST 64

typedef short bf16x8 __attribute__((ext_vector_type(8)));
typedef float f32x4 __attribute__((ext_vector_type(4)));
typedef unsigned short u16x8 __attribute__((ext_vector_type(8)));

// ws int layout
#define WS_COUNTS   0      // 64 ints
#define WS_OFFSETS  64
#define WS_NCHUNKS  192
#define WS_DESC     256    // 3 ints per chunk
#define WS_BC       8192   // [64 hist-blocks][64 species]
#define WS_ORDER    16384  // N ints
// ws byte offsets (weight panels)
#define WS_GKFRAG  (1u<<20)             // [S*16 ot][4 kk][64 lane][8] bf16 = 4MB
#define WS_LW0FRAG (5u<<20)             // [8 gt][4 kk][64][8] bf16 = 32KB
#define WS_LW1FRAG ((5u<<20) + 32768)

__device__ __forceinline__ unsigned short f2bf(float x) {
    union { float f; unsigned u; } v; v.f = x;
    unsigned r = (v.u + 0x7FFFu + ((v.u >> 16) & 1u)) >> 16;
    return (unsigned short)r;
}
__device__ __forceinline__ unsigned pack2(float a, float b) {
    return (unsigned)f2bf(a) | ((unsigned)f2bf(b) << 16);
}
__device__ __forceinline__ float bf2f(unsigned short h) {
    union { unsigned u; float f; } v; v.u = ((unsigned)h) << 16; return v.f;
}

// ---- prep: weight fragments (and zero counts) ----
__global__ __launch_bounds__(256) void k_prep(const float* __restrict__ gk,
                                              const float* __restrict__ lw0,
                                              const float* __restrict__ lw1,
                                              int* __restrict__ wsI,
                                              unsigned* __restrict__ gkfrag,
                                              unsigned* __restrict__ lw0f,
                                              unsigned* __restrict__ lw1f,
                                              int S) {
    int t = threadIdx.x, lane = t & 63, grp = t >> 6;
    int lr = lane & 15, lg = lane >> 4;
    int b = blockIdx.x;
    if (b < S) {
        const float* src = gk + (size_t)b * F * NO;
        #pragma unroll
        for (int it = 0; it < 4; ++it) {
            int ot = grp * 4 + it;
            #pragma unroll
            for (int kk = 0; kk < 4; ++kk) {
                float v[8];
                #pragma unroll
                for (int e = 0; e < 8; ++e)
                    v[e] = src[(kk * 32 + lg * 8 + e) * NO + ot * 16 + lr];
                uint4 pk;
                pk.x = pack2(v[0], v[1]); pk.y = pack2(v[2], v[3]);
                pk.z = pack2(v[4], v[5]); pk.w = pack2(v[6], v[7]);
                *(uint4*)((char*)gkfrag + ((size_t)((b * 16 + ot) * 4 + kk) * 1024) + lane * 16) = pk;
            }
        }
    } else if (b == S || b == S + 1) {
        const float* src = (b == S) ? lw0 : lw1;
        unsigned* dst = (b == S) ? lw0f : lw1f;
        const float inv = 0.08838834764831845f; // 1/sqrt(128)
        #pragma unroll
        for (int it = 0; it < 2; ++it) {
            int gt = grp * 2 + it;
            #pragma unroll
            for (int kk = 0; kk < 4; ++kk) {
                float v[8];
                #pragma unroll
                for (int e = 0; e < 8; ++e)
                    v[e] = src[(kk * 32 + lg * 8 + e) * F + gt * 16 + lr] * inv;
                uint4 pk;
                pk.x = pack2(v[0], v[1]); pk.y = pack2(v[2], v[3]);
                pk.z = pack2(v[4], v[5]); pk.w = pack2(v[6], v[7]);
                *(uint4*)((char*)dst + ((gt * 4 + kk) * 1024) + lane * 16) = pk;
            }
        }
        if (b == S && t < 64) wsI[WS_COUNTS + t] = 0;
    }
}

// ---- hist: per-block counts + global counts ----
__global__ void k_hist(const int* __restrict__ spec, int N, int* __restrict__ wsI) {
    __shared__ int h[64];
    int t = threadIdx.x, b = blockIdx.x;
    if (t < 64) h[t] = 0;
    __syncthreads();
    int per = (N + NBLK_HIST - 1) / NBLK_HIST;
    int lo = b * per, hi = min(N, lo + per);
    for (int i = lo + t; i < hi; i += 256) atomicAdd(&h[spec[i]], 1);
    __syncthreads();
    if (t < 64) {
        wsI[WS_BC + b * 64 + t] = h[t];
        if (h[t]) atomicAdd(&wsI[WS_COUNTS + t], h[t]);
    }
}

// ---- plan: prefix sums, per-block bases, chunk descriptors ----
__global__ void k_plan(int* __restrict__ wsI, int S) {
    int t = threadIdx.x;
    int cnt = (t < S) ? wsI[WS_COUNTS + t] : 0;
    int nch = (cnt + CHUNK - 1) / CHUNK;
    int x = cnt, y = nch;
    #pragma unroll
    for (int d = 1; d < 64; d <<= 1) {
        int vx = __shfl_up(x, d);
        int vy = __shfl_up(y, d);
        if (t >= d) { x += vx; y += vy; }
    }
    int off = x - cnt, cbase = y - nch;
    if (t < S) {
        wsI[WS_OFFSETS + t] = off;
        int run = off;
        for (int b2 = 0; b2 < NBLK_HIST; ++b2) {
            int tmp = wsI[WS_BC + b2 * 64 + t];
            wsI[WS_BC + b2 * 64 + t] = run;
            run += tmp;
        }
        for (int c = 0; c < nch; ++c) {
            int* dsc = &wsI[WS_DESC + 3 * (cbase + c)];
            dsc[0] = t;
            dsc[1] = off + c * CHUNK;
            dsc[2] = min(CHUNK, cnt - c * CHUNK);
        }
    }
    if (t == 63) wsI[WS_NCHUNKS] = y;
}

// ---- scatter: blockwise deterministic-range scatter ----
__global__ void k_scatter(const int* __restrict__ spec, int N, int* __restrict__ wsI) {
    __shared__ int cur[64];
    int t = threadIdx.x, b = blockIdx.x;
    if (t < 64) cur[t] = wsI[WS_BC + b * 64 + t];
    __syncthreads();
    int per = (N + NBLK_HIST - 1) / NBLK_HIST;
    int lo = b * per, hi = min(N, lo + per);
    for (int i = lo + t; i < hi; i += 256) {
        int pos = atomicAdd(&cur[spec[i]], 1);
        wsI[WS_ORDER + pos] = i;
    }
}

// ---- main: one 32-node chunk per block; 4 phases, 3 barriers (R13 base).
// R15 change: phase-4 y1 stores fused into float3 (dwordx3) per lane —
// the (g,d=0..2) triplet is contiguous in the output row, so one store
// instruction covers 192B contiguous per 16-lane group (3 lines touched
// once) instead of 3 dword stores touching the same 3 lines each.
__global__ __launch_bounds__(THREADS, 3) void k_main(
    const float* __restrict__ nf,
    const float* __restrict__ w0,
    const float* __restrict__ w1,
    const unsigned short* __restrict__ gkfrag,
    const float* __restrict__ gb,
    const unsigned short* __restrict__ lw0f,
    const unsigned short* __restrict__ lw1f,
    const int* __restrict__ wsI,
    float* __restrict__ out)
{
    int b = blockIdx.x;
    if (b >= wsI[WS_NCHUNKS]) return;
    int s     = wsI[WS_DESC + 3 * b];
    int start = wsI[WS_DESC + 3 * b + 1];
    int cnt   = wsI[WS_DESC + 3 * b + 2];

    __shared__ __align__(16) unsigned short s_ab[2][16 * 136];    // out0/out0g bf16 per half
    __shared__ __align__(16) unsigned short s_o1[3 * 32 * 136];   // c1*x1 (then out1g) bf16, 32 nodes
    __shared__ __align__(16) unsigned short s_gate[32 * 280];     // gate bf16, 32 nodes
    __shared__ int s_nid[CHUNK];

    int t = threadIdx.x;
    int lane = t & 63, w = t >> 6, lr = lane & 15, lg = lane >> 4;
    int nh = t >> 4, j = t & 15, f0 = 8 * j;

    if (t < CHUNK) s_nid[t] = (t < cnt) ? wsI[WS_ORDER + start + t] : -1;

    float o0h[2][8];   // out0 (pre-gate) per half, persists to phase 3

    // ---- phase 1: both halves ----
    #pragma unroll
    for (int h = 0; h < 2; ++h) {
        int n = h * 16 + nh;
        int nid = (n < cnt) ? wsI[WS_ORDER + start + n] : -1;
        const float* p = nf + (size_t)(nid >= 0 ? nid : 0) * 512;

        float x0[8], q[24], dot[8], o0[8], c1[8];
        *(float4*)&x0[0] = *(const float4*)&p[f0];
        *(float4*)&x0[4] = *(const float4*)&p[f0 + 4];
        #pragma unroll
        for (int v = 0; v < 6; ++v)
            *(float4*)&q[4 * v] = *(const float4*)&p[128 + 3 * f0 + 4 * v];
        if (nid < 0) {
            #pragma unroll
            for (int i = 0; i < 8; ++i) x0[i] = 0.f;
            #pragma unroll
            for (int i = 0; i < 24; ++i) q[i] = 0.f;
        }
        #pragma unroll
        for (int i = 0; i < 8; ++i)
            dot[i] = q[3 * i] * q[3 * i] + q[3 * i + 1] * q[3 * i + 1] + q[3 * i + 2] * q[3 * i + 2];

        {
            const float* W0 = w0 + s * 5 * F + f0;
            const float* W1 = w1 + s * 4 * F + f0;
            float wr[8];
            #define LOADW(base) { \
                *(float4*)&wr[0] = *(const float4*)&(base)[0]; \
                *(float4*)&wr[4] = *(const float4*)&(base)[4]; }
            LOADW(W0);
            #pragma unroll
            for (int i = 0; i < 8; ++i) o0[i] = x0[i] * wr[i];
            LOADW((W0 + F));
            #pragma unroll
            for (int i = 0; i < 8; ++i) o0[i] += x0[i] * x0[i] * wr[i];
            LOADW((W0 + 2 * F));
            #pragma unroll
            for (int i = 0; i < 8; ++i) o0[i] += dot[i] * wr[i];
            LOADW((W0 + 3 * F));
            #pragma unroll
            for (int i = 0; i < 8; ++i) o0[i] += x0[i] * x0[i] * x0[i] * wr[i];
            LOADW((W0 + 4 * F));
            #pragma unroll
            for (int i = 0; i < 8; ++i) o0[i] += x0[i] * dot[i] * wr[i];
            LOADW(W1);
            #pragma unroll
            for (int i = 0; i < 8; ++i) c1[i] = wr[i];
            LOADW((W1 + F));
            #pragma unroll
            for (int i = 0; i < 8; ++i) c1[i] += x0[i] * wr[i];
            LOADW((W1 + 2 * F));
            #pragma unroll
            for (int i = 0; i < 8; ++i) c1[i] += x0[i] * x0[i] * wr[i];
            LOADW((W1 + 3 * F));
            #pragma unroll
            for (int i = 0; i < 8; ++i) c1[i] += dot[i] * wr[i];
            #undef LOADW
        }
        {
            uint4 pk;
            pk.x = pack2(o0[0], o0[1]); pk.y = pack2(o0[2], o0[3]);
            pk.z = pack2(o0[4], o0[5]); pk.w = pack2(o0[6], o0[7]);
            *(uint4*)&s_ab[h][nh * 136 + f0] = pk;
        }
        // ungated products c1*x1[d] -> s_o1 (rescaled by gate in phase 3)
        #pragma unroll
        for (int d = 0; d < 3; ++d) {
            uint4 p1;
            p1.x = pack2(c1[0] * q[0 + d],  c1[1] * q[3 + d]);
            p1.y = pack2(c1[2] * q[6 + d],  c1[3] * q[9 + d]);
            p1.z = pack2(c1[4] * q[12 + d], c1[5] * q[15 + d]);
            p1.w = pack2(c1[6] * q[18 + d], c1[7] * q[21 + d]);
            *(uint4*)&s_o1[(d * 32 + n) * 136 + f0] = p1;
        }
        #pragma unroll
        for (int i = 0; i < 8; ++i) o0h[h][i] = o0[i];
    }
    __syncthreads();   // B1: out0 + products ready (32 nodes)

    // ---- phase 2: gate for ALL 32 nodes; panel frags loaded once (JIT) ----
    {
        #pragma unroll
        for (int oi = 0; oi < 4; ++oi) {
            const unsigned short* gkb =
                gkfrag + ((size_t)((s * 16 + 4 * w + oi) * 4)) * 512 + lane * 8;
            bf16x8 Bf[4];
            #pragma unroll
            for (int kk = 0; kk < 4; ++kk)
                Bf[kk] = *(const bf16x8*)(gkb + kk * 512);
            float gbv = gb[s * NO + (4 * w + oi) * 16 + lr];
            #pragma unroll
            for (int nt = 0; nt < 2; ++nt) {
                f32x4 acc; acc[0] = gbv; acc[1] = gbv; acc[2] = gbv; acc[3] = gbv;
                #pragma unroll
                for (int kk = 0; kk < 4; ++kk) {
                    bf16x8 A = *(const bf16x8*)&s_ab[nt][lr * 136 + kk * 32 + lg * 8];
                    acc = __builtin_amdgcn_mfma_f32_16x16x32_bf16(A, Bf[kk], acc, 0, 0, 0);
                }
                #pragma unroll
                for (int r = 0; r < 4; ++r)
                    s_gate[(nt * 16 + lg * 4 + r) * 280 + (4 * w + oi) * 16 + lr] = f2bf(acc[r]);
            }
        }
    }
    __syncthreads();   // B2: gate ready (and all phase-2 LDS reads done)

    // ---- phase 3: apply gate in place ----
    #pragma unroll
    for (int h = 0; h < 2; ++h) {
        int n = h * 16 + nh;
        float g0[8], g1[8];
        u16x8 va = *(const u16x8*)&s_gate[n * 280 + f0];
        u16x8 vb = *(const u16x8*)&s_gate[n * 280 + 128 + f0];
        #pragma unroll
        for (int i = 0; i < 8; ++i) { g0[i] = bf2f(va[i]); g1[i] = bf2f(vb[i]); }
        {
            uint4 pk;
            pk.x = pack2(o0h[h][0] * g0[0], o0h[h][1] * g0[1]);
            pk.y = pack2(o0h[h][2] * g0[2], o0h[h][3] * g0[3]);
            pk.z = pack2(o0h[h][4] * g0[4], o0h[h][5] * g0[5]);
            pk.w = pack2(o0h[h][6] * g0[6], o0h[h][7] * g0[7]);
            *(uint4*)&s_ab[h][nh * 136 + f0] = pk;
        }
        #pragma unroll
        for (int d = 0; d < 3; ++d) {
            unsigned short* pp = &s_o1[(d * 32 + n) * 136 + f0];
            u16x8 pr = *(const u16x8*)pp;
            uint4 pk;
            pk.x = pack2(bf2f(pr[0]) * g1[0], bf2f(pr[1]) * g1[1]);
            pk.y = pack2(bf2f(pr[2]) * g1[2], bf2f(pr[3]) * g1[3]);
            pk.z = pack2(bf2f(pr[4]) * g1[4], bf2f(pr[5]) * g1[5]);
            pk.w = pack2(bf2f(pr[6]) * g1[6], bf2f(pr[7]) * g1[7]);
            *(uint4*)pp = pk;
        }
    }
    __syncthreads();   // B3: out0g/out1g ready

    // ---- phase 4: y0/y1 MFMA for all 32 nodes; y1 via fused float3 stores ----
    {
        int nids[2][4];
        #pragma unroll
        for (int nt = 0; nt < 2; ++nt)
            #pragma unroll
            for (int r = 0; r < 4; ++r)
                nids[nt][r] = s_nid[nt * 16 + lg * 4 + r];

        #pragma unroll
        for (int gi = 0; gi < 2; ++gi) {
            const unsigned short* l0b =
                lw0f + (size_t)(((2 * w + gi) * 4)) * 512 + lane * 8;
            bf16x8 Lf[4];
            #pragma unroll
            for (int kk = 0; kk < 4; ++kk)
                Lf[kk] = *(const bf16x8*)(l0b + kk * 512);
            #pragma unroll
            for (int nt = 0; nt < 2; ++nt) {
                f32x4 acc = {0.f, 0.f, 0.f, 0.f};
                #pragma unroll
                for (int kk = 0; kk < 4; ++kk) {
                    bf16x8 A2 = *(const bf16x8*)&s_ab[nt][lr * 136 + kk * 32 + lg * 8];
                    acc = __builtin_amdgcn_mfma_f32_16x16x32_bf16(A2, Lf[kk], acc, 0, 0, 0);
                }
                #pragma unroll
                for (int r = 0; r < 4; ++r)
                    if (nids[nt][r] >= 0)
                        out[(size_t)nids[nt][r] * 512 + w * 32 + gi * 16 + lr] = acc[r];
            }
        }
        #pragma unroll
        for (int gi = 0; gi < 2; ++gi) {
            const unsigned short* l1b =
                lw1f + (size_t)(((2 * w + gi) * 4)) * 512 + lane * 8;
            bf16x8 Lf1[4];
            #pragma unroll
            for (int kk = 0; kk < 4; ++kk)
                Lf1[kk] = *(const bf16x8*)(l1b + kk * 512);
            #pragma unroll
            for (int nt = 0; nt < 2; ++nt) {
                f32x4 acc3[3];   // all 3 d-accumulators live -> fused stores
                #pragma unroll
                for (int d = 0; d < 3; ++d) {
                    f32x4 acc = {0.f, 0.f, 0.f, 0.f};
                    #pragma unroll
                    for (int kk = 0; kk < 4; ++kk) {
                        bf16x8 Ad = *(const bf16x8*)&s_o1[(d * 32 + nt * 16 + lr) * 136 + kk * 32 + lg * 8];
                        acc = __builtin_amdgcn_mfma_f32_16x16x32_bf16(Ad, Lf1[kk], acc, 0, 0, 0);
                    }
                    acc3[d] = acc;
                }
                #pragma unroll
                for (int r = 0; r < 4; ++r)
                    if (nids[nt][r] >= 0) {
                        float3 v;
                        v.x = acc3[0][r]; v.y = acc3[1][r]; v.z = acc3[2][r];
                        *(float3*)&out[(size_t)nids[nt][r] * 512 + F + (w * 32 + gi * 16 + lr) * 3] = v;
                    }
            }
        }
    }
}

extern "C" void kernel_launch(void* const* d_in, const int* in_sizes, int n_in,
                              void* d_out, int out_size, void* d_ws, size_t ws_size,
                              hipStream_t stream) {
    const float* nf  = (const float*)d_in[0];
    const int*  spec = (const int*)d_in[1];
    const float* w0  = (const float*)d_in[2];
    const float* w1  = (const float*)d_in[3];
    const float* gk  = (const float*)d_in[4];
    const float* gb  = (const float*)d_in[5];
    const float* lw0 = (const float*)d_in[6];
    const float* lw1 = (const float*)d_in[7];
    float* out = (float*)d_out;

    int N = in_sizes[0] / (4 * F);
    int S = in_sizes[5] / NO;
    int* wsI = (int*)d_ws;
    unsigned* gkfrag = (unsigned*)((char*)d_ws + WS_GKFRAG);
    unsigned* lw0f   = (unsigned*)((char*)d_ws + WS_LW0FRAG);
    unsigned* lw1f   = (unsigned*)((char*)d_ws + WS_LW1FRAG);

    k_prep<<<S + 2, 256, 0, stream>>>(gk, lw0, lw1, wsI, gkfrag, lw0f, lw1f, S);
    k_hist<<<NBLK_HIST, 256, 0, stream>>>(spec, N, wsI);
    k_plan<<<1, 64, 0, stream>>>(wsI, S);
    k_scatter<<<NBLK_HIST, 256, 0, stream>>>(spec, N, wsI);

    int maxc = (N + CHUNK - 1) / CHUNK + S;
    k_main<<<maxc, THREADS, 0, stream>>>(nf, w0, w1,
                                         (const unsigned short*)gkfrag, gb,
                                         (const unsigned short*)lw0f,
                                         (const unsigned short*)lw1f,
                                         wsI, out);
}